// Round 13
// baseline (192.577 us; speedup 1.0000x reference)
//
#include <hip/hip_runtime.h>
#include <cstdint>
#include <cstddef>

typedef __bf16 bf16;
typedef __bf16 bf16x8 __attribute__((ext_vector_type(8)));
typedef float f32x4 __attribute__((ext_vector_type(4)));

#define DEVI static __device__ __forceinline__

// pack two f32 -> two bf16 (RTNE) in one uint
DEVI unsigned int cvt_pk_bf16(float lo, float hi) {
  unsigned int bl = __float_as_uint(lo);
  bl += 0x7fffu + ((bl >> 16) & 1u);
  unsigned int bh = __float_as_uint(hi);
  bh += 0x7fffu + ((bh >> 16) & 1u);
  return (bl >> 16) | (bh & 0xffff0000u);
}
DEVI float bf_lo(unsigned int u) { return __uint_as_float(u << 16); }
DEVI float bf_hi(unsigned int u) { return __uint_as_float(u & 0xffff0000u); }

// async global->LDS, 16B per lane; LDS dest = wave-uniform base + lane*16
DEVI void gload16(const bf16* g, bf16* l) {
  __builtin_amdgcn_global_load_lds(
      (const __attribute__((address_space(1))) unsigned int*)g,
      (__attribute__((address_space(3))) unsigned int*)l, 16, 0, 0);
}

// ---------------------------------------------------------------------------
// Fused prepass: bid<1024 -> W transpose (f32 [k][n] -> bf16 [n][k]);
// bid>=1024 -> Q/K/V f32 -> bf16 row-major. One launch, overlapped.
// Ts stride 66 bf16 (132 B = 4 dw mod 32): transpose writes ~2-4-way banks.
// ---------------------------------------------------------------------------
__global__ __launch_bounds__(256) void prep_k(
    const float* __restrict__ Wq, const float* __restrict__ Wk,
    const float* __restrict__ Wv, const float* __restrict__ Wo,
    const float* __restrict__ Q, const float* __restrict__ K,
    const float* __restrict__ V, bf16* __restrict__ Wt,
    bf16* __restrict__ Ab)
{
  __shared__ bf16 Ts[64 * 66];
  const int bid = blockIdx.x, tid = threadIdx.x;
  if (bid < 1024) {
    const int z = bid >> 8;
    const float* W = (z == 0) ? Wq : (z == 1) ? Wk : (z == 2) ? Wv : Wo;
    bf16* out = Wt + ((size_t)z << 20);
    const int n0 = (bid & 15) * 64, k0 = ((bid >> 4) & 15) * 64;
    #pragma unroll
    for (int i = 0; i < 4; ++i) {
      int t = tid + i * 256;
      int kr = t >> 4, nc = t & 15;
      float4 v = *(const float4*)(W + (size_t)(k0 + kr) * 1024 + n0 + nc * 4);
      Ts[(nc * 4 + 0) * 66 + kr] = (bf16)v.x;
      Ts[(nc * 4 + 1) * 66 + kr] = (bf16)v.y;
      Ts[(nc * 4 + 2) * 66 + kr] = (bf16)v.z;
      Ts[(nc * 4 + 3) * 66 + kr] = (bf16)v.w;
    }
    __syncthreads();
    const int n = tid >> 2, kc = tid & 3;
    *(uint4*)(out + (size_t)(n0 + n) * 1024 + k0 + kc * 16) =
        *(const uint4*)(&Ts[n * 66 + kc * 16]);
    *(uint4*)(out + (size_t)(n0 + n) * 1024 + k0 + kc * 16 + 8) =
        *(const uint4*)(&Ts[n * 66 + kc * 16 + 8]);
  } else {
    const int t = bid - 1024;              // 0..3071
    const int z = t >> 10, x = t & 1023;
    const float* A = (z == 0) ? Q : (z == 1) ? K : V;
    bf16* o = Ab + ((size_t)z << 21);
    const size_t idx = (size_t)x * 256 + tid;
    const float4 v0 = *(const float4*)(A + idx * 8);
    const float4 v1 = *(const float4*)(A + idx * 8 + 4);
    uint4 u;
    u.x = cvt_pk_bf16(v0.x, v0.y);
    u.y = cvt_pk_bf16(v0.z, v0.w);
    u.z = cvt_pk_bf16(v1.x, v1.y);
    u.w = cvt_pk_bf16(v1.z, v1.w);
    *(uint4*)(o + idx * 8) = u;
  }
}

// ---------------------------------------------------------------------------
// Fused projection GEMM, bf16 A, 128x64 tile, BK=64, 2-deep counted-vmcnt
// pipeline (vmcnt(6) + raw s_barrier; never drains to 0 in the main loop).
// grid (256,1,3): m-tile fastest -> A-stripe sharers land on one XCD.
// z=2 epilogue emits per-(tile,col) V column sums to Tsum in-register.
// ---------------------------------------------------------------------------
__global__ __launch_bounds__(256) void proj_gemm_k(
    const bf16* __restrict__ Ab, const bf16* __restrict__ Wt,
    const float* __restrict__ bq, const float* __restrict__ bk,
    const float* __restrict__ bv, bf16* __restrict__ outbase,
    float* __restrict__ Tsum)
{
  const int z = blockIdx.z;
  const bf16* A  = Ab + ((size_t)z << 21);
  const bf16* Bt = Wt + ((size_t)z << 20);
  const float* bias = (z == 0) ? bq : (z == 1) ? bk : bv;
  bf16* outb = outbase + ((size_t)z << 21);

  __shared__ __align__(16) bf16 Asm[2][8192];   // [128][64] per buffer
  __shared__ __align__(16) bf16 Bsm[2][4096];   // [64][64]  per buffer

  const int tid = threadIdx.x, lane = tid & 63, wid = tid >> 6;
  const int q4 = lane >> 4, n16 = lane & 15;
  const int wm = wid >> 1, wn = wid & 1;
  const int bid = blockIdx.x;
  const int m0 = (bid & 15) * 128, n0 = (bid >> 4) * 64;   // m fastest: XCD reuse

  const int cbase = wid * 64 + lane;
  const bf16* gA[4];
  #pragma unroll
  for (int i = 0; i < 4; ++i) {
    int cc = cbase + i * 256;
    gA[i] = A + (size_t)(m0 + (cc >> 3)) * 1024 + (((cc & 7) ^ ((cc >> 3) & 7)) << 3);
  }
  const bf16* gB[2];
  #pragma unroll
  for (int i = 0; i < 2; ++i) {
    int cc = cbase + i * 256;
    gB[i] = Bt + (size_t)(n0 + (cc >> 3)) * 1024 + (((cc & 7) ^ ((cc >> 3) & 7)) << 3);
  }
  const int swl = n16 & 7;   // read-side row swizzle key

  f32x4 acc[4][2] = {};

  // prologue: stage tiles 0 and 1 (12 load-instructions/wave in flight)
  #pragma unroll
  for (int i = 0; i < 4; ++i) gload16(gA[i], &Asm[0][i * 2048 + wid * 512]);
  #pragma unroll
  for (int i = 0; i < 2; ++i) gload16(gB[i], &Bsm[0][i * 2048 + wid * 512]);
  #pragma unroll
  for (int i = 0; i < 4; ++i) gload16(gA[i] + 64, &Asm[1][i * 2048 + wid * 512]);
  #pragma unroll
  for (int i = 0; i < 2; ++i) gload16(gB[i] + 64, &Bsm[1][i * 2048 + wid * 512]);

  int cur = 0;
  #pragma unroll 1
  for (int t = 0; t < 16; ++t) {
    if (t < 15) { asm volatile("s_waitcnt vmcnt(6)" ::: "memory"); }
    else        { asm volatile("s_waitcnt vmcnt(0)" ::: "memory"); }
    __builtin_amdgcn_sched_barrier(0);
    __builtin_amdgcn_s_barrier();        // all waves' tile-t loads arrived
    const char* ab = (const char*)&Asm[cur][0];
    const char* bb = (const char*)&Bsm[cur][0];
    bf16x8 af[2][4], bfv[2][2];
    #pragma unroll
    for (int kk2 = 0; kk2 < 2; ++kk2) {
      #pragma unroll
      for (int rt = 0; rt < 4; ++rt)
        af[kk2][rt] = *(const bf16x8*)(ab + (wm * 64 + rt * 16 + n16) * 128 +
                                       (((kk2 * 4 + q4) ^ swl) << 4));
      #pragma unroll
      for (int ct = 0; ct < 2; ++ct)
        bfv[kk2][ct] = *(const bf16x8*)(bb + (wn * 32 + ct * 16 + n16) * 128 +
                                        (((kk2 * 4 + q4) ^ swl) << 4));
    }
    asm volatile("s_waitcnt lgkmcnt(0)" ::: "memory");
    __builtin_amdgcn_sched_barrier(0);
    __builtin_amdgcn_s_barrier();        // all waves done READING buf[cur]
    if (t < 14) {                        // stage tile t+2 into buf[cur]
      const int kc = (t + 2) * 64;
      #pragma unroll
      for (int i = 0; i < 4; ++i) gload16(gA[i] + kc, &Asm[cur][i * 2048 + wid * 512]);
      #pragma unroll
      for (int i = 0; i < 2; ++i) gload16(gB[i] + kc, &Bsm[cur][i * 2048 + wid * 512]);
    }
    #pragma unroll
    for (int kk2 = 0; kk2 < 2; ++kk2)
      #pragma unroll
      for (int rt = 0; rt < 4; ++rt)
        #pragma unroll
        for (int ct = 0; ct < 2; ++ct)
          acc[rt][ct] = __builtin_amdgcn_mfma_f32_16x16x32_bf16(af[kk2][rt], bfv[kk2][ct], acc[rt][ct], 0, 0, 0);
    cur ^= 1;
  }

  if (z < 2) {   // (B,H,S,HD)
    const int h = n0 >> 6;
    #pragma unroll
    for (int ct = 0; ct < 2; ++ct) {
      const int dl = wn * 32 + ct * 16 + n16;
      const float bvl = bias[n0 + dl];
      #pragma unroll
      for (int rt = 0; rt < 4; ++rt) {
        #pragma unroll
        for (int r = 0; r < 4; ++r) {
          int row = m0 + wm * 64 + rt * 16 + q4 * 4 + r;
          int b2 = row >> 10, s = row & 1023;
          outb[((size_t)((b2 * 16 + h) * 1024 + s) << 6) + dl] =
              (bf16)(acc[rt][ct][r] + bvl);
        }
      }
    }
  } else {       // V2 fragment layout + in-register column sums -> Tsum
    const int b2 = m0 >> 10, kt0 = (m0 & 1023) >> 6, hh = n0 >> 6;
    bf16* vout = outb + ((size_t)(b2 * 16 + hh) << 16) + (size_t)(kt0 + wm) * 4096;
    float csum[2] = {0.f, 0.f};
    #pragma unroll
    for (int rt = 0; rt < 4; ++rt) {
      const int kk = rt >> 1;
      const int q4c = (rt & 1) * 2 + (q4 >> 1);
      const int jo = (q4 & 1) * 4;
      #pragma unroll
      for (int ct = 0; ct < 2; ++ct) {
        const int cl = wn * 32 + ct * 16 + n16;
        const float bvl = bias[n0 + cl];
        unsigned int p0 = cvt_pk_bf16(acc[rt][ct][0] + bvl, acc[rt][ct][1] + bvl);
        unsigned int p1 = cvt_pk_bf16(acc[rt][ct][2] + bvl, acc[rt][ct][3] + bvl);
        csum[ct] += bf_lo(p0) + bf_hi(p0) + bf_lo(p1) + bf_hi(p1);
        *(uint2*)(vout + kk * 2048 + (wn * 2 + ct) * 512 + (q4c * 16 + n16) * 8 + jo) =
            make_uint2(p0, p1);
      }
    }
    #pragma unroll
    for (int ct = 0; ct < 2; ++ct) {
      csum[ct] += __shfl_xor(csum[ct], 16);
      csum[ct] += __shfl_xor(csum[ct], 32);
    }
    if (lane < 16) {
      float* tsd = Tsum + ((size_t)(b2 * 16 + hh) * 16 + kt0 + wm) * 64 + wn * 32 + n16;
      tsd[0]  = csum[0];
      tsd[16] = csum[1];
    }
  }
}

// ---------------------------------------------------------------------------
// Output GEMM: d_out = oat(2048x1024 bf16) @ WoT + bo, f32 out.
// NOW 128x64 tile (mirror of proj): grid 256, vmcnt(6) 2-deep pipeline.
// Halves B-operand L2 traffic (32 vs 64 MB) and doubles MFMA/barrier
// amortization vs the old 64x64. 1 block/CU — pipeline covers latency.
// ---------------------------------------------------------------------------
__global__ __launch_bounds__(256) void out_gemm_k(
    const bf16* __restrict__ Ab, const bf16* __restrict__ Bt,
    const float* __restrict__ bias, float* __restrict__ outf)
{
  __shared__ __align__(16) bf16 Asm[2][8192];   // [128][64] per buffer
  __shared__ __align__(16) bf16 Bsm[2][4096];   // [64][64]  per buffer
  const int tid = threadIdx.x, lane = tid & 63, wid = tid >> 6;
  const int q4 = lane >> 4, n16 = lane & 15;
  const int wm = wid >> 1, wn = wid & 1;
  const int bid = blockIdx.x;
  const int m0 = (bid & 15) * 128, n0 = (bid >> 4) * 64;   // m fastest: XCD reuse

  const int cbase = wid * 64 + lane;
  const bf16* gA[4];
  #pragma unroll
  for (int i = 0; i < 4; ++i) {
    int cc = cbase + i * 256;
    gA[i] = Ab + (size_t)(m0 + (cc >> 3)) * 1024 + (((cc & 7) ^ ((cc >> 3) & 7)) << 3);
  }
  const bf16* gB[2];
  #pragma unroll
  for (int i = 0; i < 2; ++i) {
    int cc = cbase + i * 256;
    gB[i] = Bt + (size_t)(n0 + (cc >> 3)) * 1024 + (((cc & 7) ^ ((cc >> 3) & 7)) << 3);
  }
  const int swl = n16 & 7;
  f32x4 acc[4][2] = {};

  #pragma unroll
  for (int i = 0; i < 4; ++i) gload16(gA[i], &Asm[0][i * 2048 + wid * 512]);
  #pragma unroll
  for (int i = 0; i < 2; ++i) gload16(gB[i], &Bsm[0][i * 2048 + wid * 512]);
  #pragma unroll
  for (int i = 0; i < 4; ++i) gload16(gA[i] + 64, &Asm[1][i * 2048 + wid * 512]);
  #pragma unroll
  for (int i = 0; i < 2; ++i) gload16(gB[i] + 64, &Bsm[1][i * 2048 + wid * 512]);

  int cur = 0;
  #pragma unroll 1
  for (int t = 0; t < 16; ++t) {
    if (t < 15) { asm volatile("s_waitcnt vmcnt(6)" ::: "memory"); }
    else        { asm volatile("s_waitcnt vmcnt(0)" ::: "memory"); }
    __builtin_amdgcn_sched_barrier(0);
    __builtin_amdgcn_s_barrier();
    const char* ab = (const char*)&Asm[cur][0];
    const char* bb = (const char*)&Bsm[cur][0];
    bf16x8 af[2][4], bfv[2][2];
    #pragma unroll
    for (int kk2 = 0; kk2 < 2; ++kk2) {
      #pragma unroll
      for (int rt = 0; rt < 4; ++rt)
        af[kk2][rt] = *(const bf16x8*)(ab + (wm * 64 + rt * 16 + n16) * 128 +
                                       (((kk2 * 4 + q4) ^ swl) << 4));
      #pragma unroll
      for (int ct = 0; ct < 2; ++ct)
        bfv[kk2][ct] = *(const bf16x8*)(bb + (wn * 32 + ct * 16 + n16) * 128 +
                                        (((kk2 * 4 + q4) ^ swl) << 4));
    }
    asm volatile("s_waitcnt lgkmcnt(0)" ::: "memory");
    __builtin_amdgcn_sched_barrier(0);
    __builtin_amdgcn_s_barrier();
    if (t < 14) {
      const int kc = (t + 2) * 64;
      #pragma unroll
      for (int i = 0; i < 4; ++i) gload16(gA[i] + kc, &Asm[cur][i * 2048 + wid * 512]);
      #pragma unroll
      for (int i = 0; i < 2; ++i) gload16(gB[i] + kc, &Bsm[cur][i * 2048 + wid * 512]);
    }
    #pragma unroll
    for (int kk2 = 0; kk2 < 2; ++kk2)
      #pragma unroll
      for (int rt = 0; rt < 4; ++rt)
        #pragma unroll
        for (int ct = 0; ct < 2; ++ct)
          acc[rt][ct] = __builtin_amdgcn_mfma_f32_16x16x32_bf16(af[kk2][rt], bfv[kk2][ct], acc[rt][ct], 0, 0, 0);
    cur ^= 1;
  }
  #pragma unroll
  for (int ct = 0; ct < 2; ++ct) {
    int col = n0 + wn * 32 + ct * 16 + n16;
    float bvl = bias[col];
    #pragma unroll
    for (int rt = 0; rt < 4; ++rt)
      #pragma unroll
      for (int r = 0; r < 4; ++r) {
        int row = m0 + wm * 64 + rt * 16 + q4 * 4 + r;
        outf[(size_t)row * 1024 + col] = acc[rt][ct][r] + bvl;
      }
  }
}

// ---------------------------------------------------------------------------
// K2: logits + 3x3 conv -> P = exp(conv - tile_row_max) stored in PV A-frag
// order, plus (mxt, sumP) per tile row. Kst/Ls LDS union.
// K staging via global_load_lds (linear [80][64] dest) with XOR-swizzled
// SOURCE chunk ch^(row&7); QK^T B-frag reads use chunk (q4^(brow&7)).
// Ls stride 68 floats. blockIdx.x == 151: Vtail suffix-scan piggybacked.
// ---------------------------------------------------------------------------
__global__ __launch_bounds__(320) void logits_conv_k(
    const bf16* __restrict__ qh, const bf16* __restrict__ kh,
    const float* __restrict__ kq_w, const float* __restrict__ kq_b,
    bf16* __restrict__ conv_out, float* __restrict__ tstats,
    const float* __restrict__ Tsum, float* __restrict__ Vtail)
{
  const int tt = blockIdx.x;
  const int h = blockIdx.y, b = blockIdx.z;
  if (tt == 151) {           // Vtail suffix scan for (b,h)
    const int d = threadIdx.x;
    if (d < 64) {
      float* vt = Vtail + (size_t)(b * 16 + h) * 17 * 64;
      vt[16 * 64 + d] = 0.f;
      float c = 0.f;
      #pragma unroll
      for (int kt = 15; kt >= 0; --kt) {
        c += Tsum[((size_t)(b * 16 + h) * 16 + kt) * 64 + d];
        vt[kt * 64 + d] = c;
      }
    }
    return;
  }
  int qt = 0, base = 0;
  while (qt < 15 && base + qt + 2 <= tt) { base += qt + 2; ++qt; }
  const int ct = tt - base;
  const int q0 = qt * 64, c0 = ct * 64;
  __shared__ __align__(16) char un[18432];      // union: Kst then Ls
  bf16* Kst = (bf16*)un;                        // [80][64] bf16, linear+swz
  float* Ls = (float*)un;                       // [66][68] f32, logits halo
  const int tid = threadIdx.x;
  const int lane = tid & 63, wid = tid >> 6;    // 5 waves
  const int q4 = lane >> 4, n16 = lane & 15;
  const bf16* qb = qh + ((size_t)(b * 16 + h) << 16);
  const bf16* kb = kh + ((size_t)(b * 16 + h) << 16);

  // ---- async K staging: rows c0-1 .. c0+78 (clamped), 640 16B chunks ----
  #pragma unroll
  for (int i = 0; i < 2; ++i) {
    int c = i * 320 + tid;                 // LDS chunk (row = c>>3, ch = c&7)
    int row = c >> 3, ch = c & 7;
    int br = min(max(c0 - 1 + row, 0), 1023);
    gload16(kb + br * 64 + ((ch ^ (row & 7)) << 3), &Kst[c * 8]);
  }

  // ---- A-fragments straight from global (overlap with staging DMA) ----
  const int ar = min(max(q0 - 2 + wid * 16 + n16, 0), 1023);
  bf16x8 a0 = *(const bf16x8*)(qb + ar * 64 + q4 * 8);
  bf16x8 a1 = *(const bf16x8*)(qb + ar * 64 + 32 + q4 * 8);
  __syncthreads();                         // drains vmcnt: staging arrived

  // ---- QK^T (B-frags from LDS, swizzled chunk read) ----
  f32x4 acc[5] = {};
  #pragma unroll
  for (int c5 = 0; c5 < 5; ++c5) {
    int brow = c5 * 16 + n16;
    int sk = brow & 7;
    bf16x8 b0 = *(const bf16x8*)(&Kst[brow * 64 + ((q4 ^ sk) << 3)]);
    bf16x8 b1 = *(const bf16x8*)(&Kst[brow * 64 + (((q4 + 4) ^ sk) << 3)]);
    acc[c5] = __builtin_amdgcn_mfma_f32_16x16x32_bf16(a0, b0, acc[c5], 0, 0, 0);
    acc[c5] = __builtin_amdgcn_mfma_f32_16x16x32_bf16(a1, b1, acc[c5], 0, 0, 0);
  }
  __syncthreads();   // Kst reads complete before Ls overwrites the union

  #pragma unroll
  for (int c5 = 0; c5 < 5; ++c5) {
    #pragma unroll
    for (int r = 0; r < 4; ++r) {
      int Lrow = wid * 16 + q4 * 4 + r;
      int Lcol = c5 * 16 + n16;
      if (Lrow < 66 && Lcol < 66) {
        int rg = q0 - 2 + Lrow;
        int cg = c0 - 1 + Lcol;
        float v = (cg >= 0 && cg <= rg) ? acc[c5][r] * 0.125f : 0.f;
        Ls[Lrow * 68 + Lcol] = v;
      }
    }
  }
  __syncthreads();

  if (tid < 256) {
    float w9[9];
    #pragma unroll
    for (int i = 0; i < 9; ++i) w9[i] = kq_w[h * 9 + i];
    const float bb = kq_b[h];
    const size_t tplane = (size_t)(b * 16 + h) * 151 + base + ct;
    bf16* tb = conv_out + tplane * 4096;
    float2* st = (float2*)tstats + tplane * 64;

    const int r = tid >> 2, qr = tid & 3;   // output row, 16-col quarter
    float4 R0[5], R1[5], R2[5];
    const float* L0 = &Ls[r * 68 + qr * 16];
    #pragma unroll
    for (int i = 0; i < 5; ++i) {
      R0[i] = *(const float4*)(L0 + i * 4);
      R1[i] = *(const float4*)(L0 + 68 + i * 4);
      R2[i] = *(const float4*)(L0 + 136 + i * 4);
    }
    const float* f0 = (const float*)R0;
    const float* f1 = (const float*)R1;
    const float* f2 = (const float*)R2;
    float o[16];
    #pragma unroll
    for (int jj = 0; jj < 16; ++jj)
      o[jj] = bb + w9[0]*f0[jj] + w9[1]*f0[jj+1] + w9[2]*f0[jj+2]
                 + w9[3]*f1[jj] + w9[4]*f1[jj+1] + w9[5]*f1[jj+2]
                 + w9[6]*f2[jj] + w9[7]*f2[jj+1] + w9[8]*f2[jj+2];
    float mx = o[0];
    #pragma unroll
    for (int jj = 1; jj < 16; ++jj) mx = fmaxf(mx, o[jj]);
    mx = fmaxf(mx, __shfl_xor(mx, 1));
    mx = fmaxf(mx, __shfl_xor(mx, 2));
    unsigned int p[8];
    #pragma unroll
    for (int jj = 0; jj < 8; ++jj)
      p[jj] = cvt_pk_bf16(__expf(o[2*jj] - mx), __expf(o[2*jj+1] - mx));
    // store in PV A-frag order: [sr][kk][q4*16+n16][8]
    const int kk = qr >> 1, q4b = (qr & 1) * 2, sr = r >> 4, n16r = r & 15;
    *(uint4*)(tb + (sr * 2 + kk) * 512 + (q4b * 16 + n16r) * 8)       = *(const uint4*)&p[0];
    *(uint4*)(tb + (sr * 2 + kk) * 512 + ((q4b + 1) * 16 + n16r) * 8) = *(const uint4*)&p[4];
    float s = 0.f;
    #pragma unroll
    for (int jj = 0; jj < 8; ++jj) s += bf_lo(p[jj]) + bf_hi(p[jj]);
    s += __shfl_xor(s, 1);
    s += __shfl_xor(s, 2);
    if (qr == 0) st[r] = make_float2(mx, s);
  }
}

// ---------------------------------------------------------------------------
// K3b: PV from fragment-ordered P and V2 (verified oo/kh-split), per-row
// (m, 1/l) stats computed inline (fixed-16 unroll, sentinel predication).
// Pp padded to stride 66 (~2-way banks).
// ---------------------------------------------------------------------------
__global__ __launch_bounds__(256) void pv_k(
    const bf16* __restrict__ conv_out, const bf16* __restrict__ V2,
    const float* __restrict__ tstats, const float* __restrict__ Vtail,
    const float* __restrict__ mix_w, const float* __restrict__ mix_b,
    const float* __restrict__ kq_b,
    const float* __restrict__ dyt_alpha, const float* __restrict__ dyt_w,
    const float* __restrict__ dyt_b, const float* __restrict__ depth_scale,
    bf16* __restrict__ out_attn)
{
  const int qt16 = blockIdx.x, g = blockIdx.y, b = blockIdx.z;
  const int qt = qt16 >> 2;
  const int nkt = min(qt + 2, 16);
  const int Tc = 1024 - (nkt << 6);
  const int tid = threadIdx.x, lane = tid & 63, wid = tid >> 6;
  const int q4 = lane >> 4, n16 = lane & 15;
  const int oo = wid >> 1, kh = wid & 1;
  const int h0 = 2 * g, ho = h0 + oo;
  const int sr = qt16 & 3, strow = sr * 16;
  const size_t tbase = (size_t)(qt * (qt + 3) / 2);

  // ---- inline combine: per-row (m, 1/l) for this block's 16 rows x 2 heads
  __shared__ float2 rsS[2][16];
  if (tid < 32) {
    const int hh = tid >> 4, rw = tid & 15;
    const float2* tsp = (const float2*)tstats +
        ((size_t)(b * 16 + h0 + hh) * 151 + tbase) * 64 + strow + rw;
    const float kb2 = kq_b[h0 + hh];
    float vx[16], vy[16];
    #pragma unroll
    for (int kt = 0; kt < 16; ++kt) {      // all 16 loads independent
      float2 v = tsp[(size_t)kt * 64];     // in-bounds: max idx 4831 < 4832
      vx[kt] = (kt < nkt) ? v.x : -3.0e38f;
      vy[kt] = (kt < nkt) ? v.y : 0.f;
    }
    float mx = (Tc > 0) ? kb2 : -3.0e38f;
    #pragma unroll
    for (int kt = 0; kt < 16; ++kt) mx = fmaxf(mx, vx[kt]);
    float s = (float)Tc * __expf(kb2 - mx);
    #pragma unroll
    for (int kt = 0; kt < 16; ++kt) s += vy[kt] * __expf(vx[kt] - mx);
    rsS[hh][rw] = make_float2(mx, 1.f / s);
  }
  __syncthreads();

  const float2 r0 = rsS[0][n16];
  const float2 r1 = rsS[1][n16];
  const float m0 = r0.x, m1 = r1.x;
  const float mwa = mix_w[ho * 2 + 0], mwb = mix_w[ho * 2 + 1];
  const float wa = mwa * r0.y, wb = mwb * r1.y;   // mw * rinv

  const bf16* pb0 = conv_out +
      ((size_t)(b * 16 + h0) * 151 + tbase) * 4096 + sr * 1024 + lane * 8;
  const bf16* pb1 = pb0 + (size_t)151 * 4096;
  const float2* ts0 = (const float2*)tstats +
      ((size_t)(b * 16 + h0) * 151 + tbase) * 64 + strow + n16;
  const float2* ts1 = ts0 + (size_t)151 * 64;
  const bf16* vb = V2 + ((size_t)(b * 16 + ho) << 16) + lane * 8;

  const int niter = (nkt - kh + 1) >> 1;
  float wk0[8], wk1[8];
  #pragma unroll
  for (int i = 0; i < 8; ++i) {
    int ktc = (i < niter) ? (kh + 2 * i) : 0;
    wk0[i] = wa * __expf(ts0[(size_t)ktc * 64].x - m0);
    wk1[i] = wb * __expf(ts1[(size_t)ktc * 64].x - m1);
  }

  f32x4 acc[4] = {};
  int ii = 0;
  for (int kt = kh; kt < nkt; kt += 2, ++ii) {
    uint4 u0[2], u1[2];
    #pragma unroll
    for (int kk = 0; kk < 2; ++kk) {
      u0[kk] = *(const uint4*)(pb0 + (size_t)kt * 4096 + kk * 512);
      u1[kk] = *(const uint4*)(pb1 + (size_t)kt * 4096 + kk * 512);
    }
    bf16x8 bv[2][4];
    #pragma unroll
    for (int kk = 0; kk < 2; ++kk)
      #pragma unroll
      for (int ctt = 0; ctt < 4; ++ctt)
        bv[kk][ctt] = *(const bf16x8*)(vb + (size_t)kt * 4096 + kk * 2048 + ctt * 512);
    const float w0 = wk0[ii], w1 = wk1[ii];
    #pragma unroll
    for (int kk = 0; kk < 2; ++kk) {
      bf16x8 af;
      const unsigned int* a0p = (const unsigned int*)&u0[kk];
      const unsigned int* a1p = (const unsigned int*)&u1[kk];
      #pragma unroll
      for (int i2 = 0; i2 < 4; ++i2) {
        float a0 = w0 * bf_lo(a0p[i2]) + w1 * bf_lo(a1p[i2]);
        float a1 = w0 * bf_hi(a0p[i2]) + w1 * bf_hi(a1p[i2]);
        ((unsigned int*)&af)[i2] = cvt_pk_bf16(a0, a1);
      }
      #pragma unroll
      for (int ctt = 0; ctt < 4; ++ctt)
        acc[ctt] = __builtin_amdgcn_mfma_f32_16x16x32_bf16(af, bv[kk][ctt], acc[ctt], 0, 0, 0);
    }
  }

  __shared__ float Pp[2][16][66];   // stride 66: ~2-way banks
  if (kh == 1) {
    #pragma unroll
    for (int ctt = 0; ctt < 4; ++ctt)
      #pragma unroll
      for (int r = 0; r < 4; ++r)
        Pp[oo][q4 * 4 + r][ctt * 16 + n16] = acc[ctt][r];
  }
  __syncthreads();
  if (kh == 1) return;
  #pragma unroll
  for (int ctt = 0; ctt < 4; ++ctt)
    #pragma unroll
    for (int r = 0; r < 4; ++r)
      acc[ctt][r] += Pp[oo][q4 * 4 + r][ctt * 16 + n16];

  const float kqb0 = kq_b[h0], kqb1 = kq_b[h0 + 1];
  float tw[4];
  #pragma unroll
  for (int r = 0; r < 4; ++r) {
    float2 s0 = rsS[0][q4 * 4 + r];
    float2 s1 = rsS[1][q4 * 4 + r];
    tw[r] = (Tc > 0) ? (mwa * s0.y * __expf(kqb0 - s0.x) +
                        mwb * s1.y * __expf(kqb1 - s1.x)) : 0.f;
  }
  const float mb = mix_b[ho];
  const float alpha = dyt_alpha[0], dsc = depth_scale[0];
  const float* vt = Vtail + (size_t)(b * 16 + ho) * 17 * 64;
  #pragma unroll
  for (int ctt = 0; ctt < 4; ++ctt) {
    int d = ctt * 16 + n16;
    float vtn = vt[(size_t)nkt * 64 + d];
    float vt0 = vt[d];
    float wgt = dyt_w[d], bds = dyt_b[d];
    #pragma unroll
    for (int r = 0; r < 4; ++r) {
      float v = acc[ctt][r] + tw[r] * vtn + mb * vt0;
      float e = __expf(2.f * alpha * v);
      float th = 1.f - 2.f / (e + 1.f);
      float y = (th * wgt + bds) * dsc;
      int qr = qt16 * 16 + q4 * 4 + r;
      out_attn[(((size_t)(b * 1024 + qr)) << 10) + ho * 64 + d] = (bf16)y;
    }
  }
}

// ---------------------------------------------------------------------------
extern "C" void kernel_launch(void* const* d_in, const int* in_sizes, int n_in,
                              void* d_out, int out_size, void* d_ws, size_t ws_size,
                              hipStream_t stream) {
  const float* Q    = (const float*)d_in[0];
  const float* Kx   = (const float*)d_in[1];
  const float* V    = (const float*)d_in[2];
  const float* Wq   = (const float*)d_in[3];
  const float* bq   = (const float*)d_in[4];
  const float* Wk   = (const float*)d_in[5];
  const float* bk   = (const float*)d_in[6];
  const float* Wv   = (const float*)d_in[7];
  const float* bv   = (const float*)d_in[8];
  const float* Wo   = (const float*)d_in[9];
  const float* bo   = (const float*)d_in[10];
  const float* kq_w = (const float*)d_in[11];
  const float* kq_b = (const float*)d_in[12];
  const float* mixw = (const float*)d_in[13];
  const float* mixb = (const float*)d_in[14];
  const float* dyta = (const float*)d_in[15];
  const float* dytw = (const float*)d_in[16];
  const float* dytb = (const float*)d_in[17];
  const float* dsc  = (const float*)d_in[18];

  char* ws = (char*)d_ws;
  bf16* qh     = (bf16*)(ws);                              // 4 MB (kh, V2 follow)
  float* tstat = (float*)(ws + (size_t)(12 << 20));        // 2.42 MB (alive thru pv)
  float* Vtail = (float*)(ws + (size_t)(16 << 20));        // 136 KB
  float* Tsum  = (float*)(ws + (size_t)(16 << 20) + (256 << 10)); // 128 KB
  bf16* WtT    = (bf16*)(ws + (size_t)(17 << 20));         // 8 MB (4 planes x 2MB)
  bf16* oat    = (bf16*)(ws + (size_t)(17 << 20));         // 4 MB, aliases Wq/Wk planes
  bf16* conv   = (bf16*)(ws + (size_t)(25 << 20));         // 39.58 MB (P2 tiles)
  bf16* Ab     = (bf16*)(ws + (size_t)(25 << 20));         // 12 MB, aliases conv (dead then)
  bf16* kh     = qh + ((size_t)1 << 21);
  bf16* V2     = qh + ((size_t)2 << 21);

  prep_k<<<dim3(4096), 256, 0, stream>>>(Wq, Wk, Wv, Wo, Q, Kx, V, WtT, Ab);
  proj_gemm_k<<<dim3(256, 1, 3), 256, 0, stream>>>(Ab, WtT, bq, bk, bv, qh, Tsum);
  logits_conv_k<<<dim3(152, 16, 2), 320, 0, stream>>>(qh, kh, kq_w, kq_b, conv, tstat,
                                                      Tsum, Vtail);
  pv_k<<<dim3(64, 8, 2), 256, 0, stream>>>(conv, V2, tstat, Vtail, mixw, mixb, kq_b,
                                           dyta, dytw, dytb, dsc, oat);
  out_gemm_k<<<dim3(256), 256, 0, stream>>>(oat, WtT + ((size_t)3 << 20), bo, (float*)d_out);
}

// Round 14
// 190.916 us; speedup vs baseline: 1.0087x; 1.0087x over previous
//
#include <hip/hip_runtime.h>
#include <cstdint>
#include <cstddef>

typedef __bf16 bf16;
typedef __bf16 bf16x8 __attribute__((ext_vector_type(8)));
typedef float f32x4 __attribute__((ext_vector_type(4)));

#define DEVI static __device__ __forceinline__

// pack two f32 -> two bf16 (RTNE) in one uint
DEVI unsigned int cvt_pk_bf16(float lo, float hi) {
  unsigned int bl = __float_as_uint(lo);
  bl += 0x7fffu + ((bl >> 16) & 1u);
  unsigned int bh = __float_as_uint(hi);
  bh += 0x7fffu + ((bh >> 16) & 1u);
  return (bl >> 16) | (bh & 0xffff0000u);
}
DEVI float bf_lo(unsigned int u) { return __uint_as_float(u << 16); }
DEVI float bf_hi(unsigned int u) { return __uint_as_float(u & 0xffff0000u); }

// async global->LDS, 16B per lane; LDS dest = wave-uniform base + lane*16
DEVI void gload16(const bf16* g, bf16* l) {
  __builtin_amdgcn_global_load_lds(
      (const __attribute__((address_space(1))) unsigned int*)g,
      (__attribute__((address_space(3))) unsigned int*)l, 16, 0, 0);
}

// ---------------------------------------------------------------------------
// Fused prepass: bid<1024 -> W transpose (f32 [k][n] -> bf16 [n][k]);
// bid>=1024 -> Q/K/V f32 -> bf16 row-major. One launch, overlapped.
// Ts stride 66 bf16 (132 B = 4 dw mod 32): transpose writes ~2-4-way banks.
// ---------------------------------------------------------------------------
__global__ __launch_bounds__(256) void prep_k(
    const float* __restrict__ Wq, const float* __restrict__ Wk,
    const float* __restrict__ Wv, const float* __restrict__ Wo,
    const float* __restrict__ Q, const float* __restrict__ K,
    const float* __restrict__ V, bf16* __restrict__ Wt,
    bf16* __restrict__ Ab)
{
  __shared__ bf16 Ts[64 * 66];
  const int bid = blockIdx.x, tid = threadIdx.x;
  if (bid < 1024) {
    const int z = bid >> 8;
    const float* W = (z == 0) ? Wq : (z == 1) ? Wk : (z == 2) ? Wv : Wo;
    bf16* out = Wt + ((size_t)z << 20);
    const int n0 = (bid & 15) * 64, k0 = ((bid >> 4) & 15) * 64;
    #pragma unroll
    for (int i = 0; i < 4; ++i) {
      int t = tid + i * 256;
      int kr = t >> 4, nc = t & 15;
      float4 v = *(const float4*)(W + (size_t)(k0 + kr) * 1024 + n0 + nc * 4);
      Ts[(nc * 4 + 0) * 66 + kr] = (bf16)v.x;
      Ts[(nc * 4 + 1) * 66 + kr] = (bf16)v.y;
      Ts[(nc * 4 + 2) * 66 + kr] = (bf16)v.z;
      Ts[(nc * 4 + 3) * 66 + kr] = (bf16)v.w;
    }
    __syncthreads();
    const int n = tid >> 2, kc = tid & 3;
    *(uint4*)(out + (size_t)(n0 + n) * 1024 + k0 + kc * 16) =
        *(const uint4*)(&Ts[n * 66 + kc * 16]);
    *(uint4*)(out + (size_t)(n0 + n) * 1024 + k0 + kc * 16 + 8) =
        *(const uint4*)(&Ts[n * 66 + kc * 16 + 8]);
  } else {
    const int t = bid - 1024;              // 0..3071
    const int z = t >> 10, x = t & 1023;
    const float* A = (z == 0) ? Q : (z == 1) ? K : V;
    bf16* o = Ab + ((size_t)z << 21);
    const size_t idx = (size_t)x * 256 + tid;
    const float4 v0 = *(const float4*)(A + idx * 8);
    const float4 v1 = *(const float4*)(A + idx * 8 + 4);
    uint4 u;
    u.x = cvt_pk_bf16(v0.x, v0.y);
    u.y = cvt_pk_bf16(v0.z, v0.w);
    u.z = cvt_pk_bf16(v1.x, v1.y);
    u.w = cvt_pk_bf16(v1.z, v1.w);
    *(uint4*)(o + idx * 8) = u;
  }
}

// ---------------------------------------------------------------------------
// Fused projection GEMM, bf16 A, 128x64 tile, BK=64, 2-deep counted-vmcnt
// pipeline (vmcnt(6) + raw s_barrier; never drains to 0 in the main loop).
// grid (256,1,3): m-tile fastest -> A-stripe sharers land on one XCD.
// z=2 epilogue emits per-(tile,col) V column sums to Tsum in-register.
// ---------------------------------------------------------------------------
__global__ __launch_bounds__(256) void proj_gemm_k(
    const bf16* __restrict__ Ab, const bf16* __restrict__ Wt,
    const float* __restrict__ bq, const float* __restrict__ bk,
    const float* __restrict__ bv, bf16* __restrict__ outbase,
    float* __restrict__ Tsum)
{
  const int z = blockIdx.z;
  const bf16* A  = Ab + ((size_t)z << 21);
  const bf16* Bt = Wt + ((size_t)z << 20);
  const float* bias = (z == 0) ? bq : (z == 1) ? bk : bv;
  bf16* outb = outbase + ((size_t)z << 21);

  __shared__ __align__(16) bf16 Asm[2][8192];   // [128][64] per buffer
  __shared__ __align__(16) bf16 Bsm[2][4096];   // [64][64]  per buffer

  const int tid = threadIdx.x, lane = tid & 63, wid = tid >> 6;
  const int q4 = lane >> 4, n16 = lane & 15;
  const int wm = wid >> 1, wn = wid & 1;
  const int bid = blockIdx.x;
  const int m0 = (bid & 15) * 128, n0 = (bid >> 4) * 64;   // m fastest: XCD reuse

  const int cbase = wid * 64 + lane;
  const bf16* gA[4];
  #pragma unroll
  for (int i = 0; i < 4; ++i) {
    int cc = cbase + i * 256;
    gA[i] = A + (size_t)(m0 + (cc >> 3)) * 1024 + (((cc & 7) ^ ((cc >> 3) & 7)) << 3);
  }
  const bf16* gB[2];
  #pragma unroll
  for (int i = 0; i < 2; ++i) {
    int cc = cbase + i * 256;
    gB[i] = Bt + (size_t)(n0 + (cc >> 3)) * 1024 + (((cc & 7) ^ ((cc >> 3) & 7)) << 3);
  }
  const int swl = n16 & 7;   // read-side row swizzle key

  f32x4 acc[4][2] = {};

  // prologue: stage tiles 0 and 1 (12 load-instructions/wave in flight)
  #pragma unroll
  for (int i = 0; i < 4; ++i) gload16(gA[i], &Asm[0][i * 2048 + wid * 512]);
  #pragma unroll
  for (int i = 0; i < 2; ++i) gload16(gB[i], &Bsm[0][i * 2048 + wid * 512]);
  #pragma unroll
  for (int i = 0; i < 4; ++i) gload16(gA[i] + 64, &Asm[1][i * 2048 + wid * 512]);
  #pragma unroll
  for (int i = 0; i < 2; ++i) gload16(gB[i] + 64, &Bsm[1][i * 2048 + wid * 512]);

  int cur = 0;
  #pragma unroll 1
  for (int t = 0; t < 16; ++t) {
    if (t < 15) { asm volatile("s_waitcnt vmcnt(6)" ::: "memory"); }
    else        { asm volatile("s_waitcnt vmcnt(0)" ::: "memory"); }
    __builtin_amdgcn_sched_barrier(0);
    __builtin_amdgcn_s_barrier();        // all waves' tile-t loads arrived
    const char* ab = (const char*)&Asm[cur][0];
    const char* bb = (const char*)&Bsm[cur][0];
    bf16x8 af[2][4], bfv[2][2];
    #pragma unroll
    for (int kk2 = 0; kk2 < 2; ++kk2) {
      #pragma unroll
      for (int rt = 0; rt < 4; ++rt)
        af[kk2][rt] = *(const bf16x8*)(ab + (wm * 64 + rt * 16 + n16) * 128 +
                                       (((kk2 * 4 + q4) ^ swl) << 4));
      #pragma unroll
      for (int ct = 0; ct < 2; ++ct)
        bfv[kk2][ct] = *(const bf16x8*)(bb + (wn * 32 + ct * 16 + n16) * 128 +
                                        (((kk2 * 4 + q4) ^ swl) << 4));
    }
    asm volatile("s_waitcnt lgkmcnt(0)" ::: "memory");
    __builtin_amdgcn_sched_barrier(0);
    __builtin_amdgcn_s_barrier();        // all waves done READING buf[cur]
    if (t < 14) {                        // stage tile t+2 into buf[cur]
      const int kc = (t + 2) * 64;
      #pragma unroll
      for (int i = 0; i < 4; ++i) gload16(gA[i] + kc, &Asm[cur][i * 2048 + wid * 512]);
      #pragma unroll
      for (int i = 0; i < 2; ++i) gload16(gB[i] + kc, &Bsm[cur][i * 2048 + wid * 512]);
    }
    #pragma unroll
    for (int kk2 = 0; kk2 < 2; ++kk2)
      #pragma unroll
      for (int rt = 0; rt < 4; ++rt)
        #pragma unroll
        for (int ct = 0; ct < 2; ++ct)
          acc[rt][ct] = __builtin_amdgcn_mfma_f32_16x16x32_bf16(af[kk2][rt], bfv[kk2][ct], acc[rt][ct], 0, 0, 0);
    cur ^= 1;
  }

  if (z < 2) {   // (B,H,S,HD)
    const int h = n0 >> 6;
    #pragma unroll
    for (int ct = 0; ct < 2; ++ct) {
      const int dl = wn * 32 + ct * 16 + n16;
      const float bvl = bias[n0 + dl];
      #pragma unroll
      for (int rt = 0; rt < 4; ++rt) {
        #pragma unroll
        for (int r = 0; r < 4; ++r) {
          int row = m0 + wm * 64 + rt * 16 + q4 * 4 + r;
          int b2 = row >> 10, s = row & 1023;
          outb[((size_t)((b2 * 16 + h) * 1024 + s) << 6) + dl] =
              (bf16)(acc[rt][ct][r] + bvl);
        }
      }
    }
  } else {       // V2 fragment layout + in-register column sums -> Tsum
    const int b2 = m0 >> 10, kt0 = (m0 & 1023) >> 6, hh = n0 >> 6;
    bf16* vout = outb + ((size_t)(b2 * 16 + hh) << 16) + (size_t)(kt0 + wm) * 4096;
    float csum[2] = {0.f, 0.f};
    #pragma unroll
    for (int rt = 0; rt < 4; ++rt) {
      const int kk = rt >> 1;
      const int q4c = (rt & 1) * 2 + (q4 >> 1);
      const int jo = (q4 & 1) * 4;
      #pragma unroll
      for (int ct = 0; ct < 2; ++ct) {
        const int cl = wn * 32 + ct * 16 + n16;
        const float bvl = bias[n0 + cl];
        unsigned int p0 = cvt_pk_bf16(acc[rt][ct][0] + bvl, acc[rt][ct][1] + bvl);
        unsigned int p1 = cvt_pk_bf16(acc[rt][ct][2] + bvl, acc[rt][ct][3] + bvl);
        csum[ct] += bf_lo(p0) + bf_hi(p0) + bf_lo(p1) + bf_hi(p1);
        *(uint2*)(vout + kk * 2048 + (wn * 2 + ct) * 512 + (q4c * 16 + n16) * 8 + jo) =
            make_uint2(p0, p1);
      }
    }
    #pragma unroll
    for (int ct = 0; ct < 2; ++ct) {
      csum[ct] += __shfl_xor(csum[ct], 16);
      csum[ct] += __shfl_xor(csum[ct], 32);
    }
    if (lane < 16) {
      float* tsd = Tsum + ((size_t)(b2 * 16 + hh) * 16 + kt0 + wm) * 64 + wn * 32 + n16;
      tsd[0]  = csum[0];
      tsd[16] = csum[1];
    }
  }
}

// ---------------------------------------------------------------------------
// Output GEMM: d_out = oat(2048x1024 bf16) @ WoT + bo, f32 out.
// 64x64 tile, BK=64, 2-deep counted-vmcnt pipeline (vmcnt(4)). 512 blocks
// (= 2/CU; r13 showed 128x64 @1 block/CU loses the SIMD interleave).
// ---------------------------------------------------------------------------
__global__ __launch_bounds__(256) void out_gemm_k(
    const bf16* __restrict__ Ab, const bf16* __restrict__ Bt,
    const float* __restrict__ bias, float* __restrict__ outf)
{
  __shared__ __align__(16) bf16 Asm[2][4096];
  __shared__ __align__(16) bf16 Bsm[2][4096];
  const int tid = threadIdx.x, lane = tid & 63, wid = tid >> 6;
  const int q4 = lane >> 4, n16 = lane & 15;
  const int wm = wid >> 1, wn = wid & 1;
  const int bid = blockIdx.x;
  const int m0 = (bid & 31) * 64, n0 = (bid >> 5) * 64;   // XCD swizzle
  const int cbase = wid * 64 + lane;
  const bf16* gA[2];
  const bf16* gB[2];
  #pragma unroll
  for (int i = 0; i < 2; ++i) {
    int cc = cbase + i * 256;
    gA[i] = Ab + (size_t)(m0 + (cc >> 3)) * 1024 + (((cc & 7) ^ ((cc >> 3) & 7)) << 3);
    gB[i] = Bt + (size_t)(n0 + (cc >> 3)) * 1024 + (((cc & 7) ^ ((cc >> 3) & 7)) << 3);
  }
  const int swl = n16 & 7;
  f32x4 acc[2][2] = {};

  #pragma unroll
  for (int i = 0; i < 2; ++i) {
    gload16(gA[i], &Asm[0][i * 2048 + wid * 512]);
    gload16(gB[i], &Bsm[0][i * 2048 + wid * 512]);
  }
  #pragma unroll
  for (int i = 0; i < 2; ++i) {
    gload16(gA[i] + 64, &Asm[1][i * 2048 + wid * 512]);
    gload16(gB[i] + 64, &Bsm[1][i * 2048 + wid * 512]);
  }

  int cur = 0;
  #pragma unroll 1
  for (int t = 0; t < 16; ++t) {
    if (t < 15) { asm volatile("s_waitcnt vmcnt(4)" ::: "memory"); }
    else        { asm volatile("s_waitcnt vmcnt(0)" ::: "memory"); }
    __builtin_amdgcn_sched_barrier(0);
    __builtin_amdgcn_s_barrier();
    const char* ab = (const char*)&Asm[cur][0];
    const char* bb = (const char*)&Bsm[cur][0];
    bf16x8 af[2][2], bfv[2][2];
    #pragma unroll
    for (int kk2 = 0; kk2 < 2; ++kk2) {
      #pragma unroll
      for (int rt = 0; rt < 2; ++rt)
        af[kk2][rt] = *(const bf16x8*)(ab + (wm * 32 + rt * 16 + n16) * 128 +
                                       (((kk2 * 4 + q4) ^ swl) << 4));
      #pragma unroll
      for (int ct = 0; ct < 2; ++ct)
        bfv[kk2][ct] = *(const bf16x8*)(bb + (wn * 32 + ct * 16 + n16) * 128 +
                                        (((kk2 * 4 + q4) ^ swl) << 4));
    }
    asm volatile("s_waitcnt lgkmcnt(0)" ::: "memory");
    __builtin_amdgcn_sched_barrier(0);
    __builtin_amdgcn_s_barrier();
    if (t < 14) {
      const int kc = (t + 2) * 64;
      #pragma unroll
      for (int i = 0; i < 2; ++i) {
        gload16(gA[i] + kc, &Asm[cur][i * 2048 + wid * 512]);
        gload16(gB[i] + kc, &Bsm[cur][i * 2048 + wid * 512]);
      }
    }
    #pragma unroll
    for (int kk2 = 0; kk2 < 2; ++kk2)
      #pragma unroll
      for (int rt = 0; rt < 2; ++rt)
        #pragma unroll
        for (int ct = 0; ct < 2; ++ct)
          acc[rt][ct] = __builtin_amdgcn_mfma_f32_16x16x32_bf16(af[kk2][rt], bfv[kk2][ct], acc[rt][ct], 0, 0, 0);
    cur ^= 1;
  }
  #pragma unroll
  for (int ct = 0; ct < 2; ++ct) {
    int col = n0 + wn * 32 + ct * 16 + n16;
    float bvl = bias[col];
    #pragma unroll
    for (int rt = 0; rt < 2; ++rt)
      #pragma unroll
      for (int r = 0; r < 4; ++r) {
        int row = m0 + wm * 32 + rt * 16 + q4 * 4 + r;
        outf[(size_t)row * 1024 + col] = acc[rt][ct][r] + bvl;
      }
  }
}

// ---------------------------------------------------------------------------
// K2: logits + 3x3 conv -> P = exp(conv - tile_row_max) stored in PV A-frag
// order, plus (mxt, sumP) per tile row. Kst/Ls LDS union.
// K staging via global_load_lds (linear [80][64] dest) with XOR-swizzled
// SOURCE chunk ch^(row&7); QK^T B-frag reads use chunk (q4^(brow&7)).
// Ls stride 68 floats. blockIdx.x == 151: Vtail suffix-scan piggybacked.
// ---------------------------------------------------------------------------
__global__ __launch_bounds__(320) void logits_conv_k(
    const bf16* __restrict__ qh, const bf16* __restrict__ kh,
    const float* __restrict__ kq_w, const float* __restrict__ kq_b,
    bf16* __restrict__ conv_out, float* __restrict__ tstats,
    const float* __restrict__ Tsum, float* __restrict__ Vtail)
{
  const int tt = blockIdx.x;
  const int h = blockIdx.y, b = blockIdx.z;
  if (tt == 151) {           // Vtail suffix scan for (b,h)
    const int d = threadIdx.x;
    if (d < 64) {
      float* vt = Vtail + (size_t)(b * 16 + h) * 17 * 64;
      vt[16 * 64 + d] = 0.f;
      float c = 0.f;
      #pragma unroll
      for (int kt = 15; kt >= 0; --kt) {
        c += Tsum[((size_t)(b * 16 + h) * 16 + kt) * 64 + d];
        vt[kt * 64 + d] = c;
      }
    }
    return;
  }
  int qt = 0, base = 0;
  while (qt < 15 && base + qt + 2 <= tt) { base += qt + 2; ++qt; }
  const int ct = tt - base;
  const int q0 = qt * 64, c0 = ct * 64;
  __shared__ __align__(16) char un[18432];      // union: Kst then Ls
  bf16* Kst = (bf16*)un;                        // [80][64] bf16, linear+swz
  float* Ls = (float*)un;                       // [66][68] f32, logits halo
  const int tid = threadIdx.x;
  const int lane = tid & 63, wid = tid >> 6;    // 5 waves
  const int q4 = lane >> 4, n16 = lane & 15;
  const bf16* qb = qh + ((size_t)(b * 16 + h) << 16);
  const bf16* kb = kh + ((size_t)(b * 16 + h) << 16);

  // ---- async K staging: rows c0-1 .. c0+78 (clamped), 640 16B chunks ----
  #pragma unroll
  for (int i = 0; i < 2; ++i) {
    int c = i * 320 + tid;                 // LDS chunk (row = c>>3, ch = c&7)
    int row = c >> 3, ch = c & 7;
    int br = min(max(c0 - 1 + row, 0), 1023);
    gload16(kb + br * 64 + ((ch ^ (row & 7)) << 3), &Kst[c * 8]);
  }

  // ---- A-fragments straight from global (overlap with staging DMA) ----
  const int ar = min(max(q0 - 2 + wid * 16 + n16, 0), 1023);
  bf16x8 a0 = *(const bf16x8*)(qb + ar * 64 + q4 * 8);
  bf16x8 a1 = *(const bf16x8*)(qb + ar * 64 + 32 + q4 * 8);
  __syncthreads();                         // drains vmcnt: staging arrived

  // ---- QK^T (B-frags from LDS, swizzled chunk read) ----
  f32x4 acc[5] = {};
  #pragma unroll
  for (int c5 = 0; c5 < 5; ++c5) {
    int brow = c5 * 16 + n16;
    int sk = brow & 7;
    bf16x8 b0 = *(const bf16x8*)(&Kst[brow * 64 + ((q4 ^ sk) << 3)]);
    bf16x8 b1 = *(const bf16x8*)(&Kst[brow * 64 + (((q4 + 4) ^ sk) << 3)]);
    acc[c5] = __builtin_amdgcn_mfma_f32_16x16x32_bf16(a0, b0, acc[c5], 0, 0, 0);
    acc[c5] = __builtin_amdgcn_mfma_f32_16x16x32_bf16(a1, b1, acc[c5], 0, 0, 0);
  }
  __syncthreads();   // Kst reads complete before Ls overwrites the union

  #pragma unroll
  for (int c5 = 0; c5 < 5; ++c5) {
    #pragma unroll
    for (int r = 0; r < 4; ++r) {
      int Lrow = wid * 16 + q4 * 4 + r;
      int Lcol = c5 * 16 + n16;
      if (Lrow < 66 && Lcol < 66) {
        int rg = q0 - 2 + Lrow;
        int cg = c0 - 1 + Lcol;
        float v = (cg >= 0 && cg <= rg) ? acc[c5][r] * 0.125f : 0.f;
        Ls[Lrow * 68 + Lcol] = v;
      }
    }
  }
  __syncthreads();

  if (tid < 256) {
    float w9[9];
    #pragma unroll
    for (int i = 0; i < 9; ++i) w9[i] = kq_w[h * 9 + i];
    const float bb = kq_b[h];
    const size_t tplane = (size_t)(b * 16 + h) * 151 + base + ct;
    bf16* tb = conv_out + tplane * 4096;
    float2* st = (float2*)tstats + tplane * 64;

    const int r = tid >> 2, qr = tid & 3;   // output row, 16-col quarter
    float4 R0[5], R1[5], R2[5];
    const float* L0 = &Ls[r * 68 + qr * 16];
    #pragma unroll
    for (int i = 0; i < 5; ++i) {
      R0[i] = *(const float4*)(L0 + i * 4);
      R1[i] = *(const float4*)(L0 + 68 + i * 4);
      R2[i] = *(const float4*)(L0 + 136 + i * 4);
    }
    const float* f0 = (const float*)R0;
    const float* f1 = (const float*)R1;
    const float* f2 = (const float*)R2;
    float o[16];
    #pragma unroll
    for (int jj = 0; jj < 16; ++jj)
      o[jj] = bb + w9[0]*f0[jj] + w9[1]*f0[jj+1] + w9[2]*f0[jj+2]
                 + w9[3]*f1[jj] + w9[4]*f1[jj+1] + w9[5]*f1[jj+2]
                 + w9[6]*f2[jj] + w9[7]*f2[jj+1] + w9[8]*f2[jj+2];
    float mx = o[0];
    #pragma unroll
    for (int jj = 1; jj < 16; ++jj) mx = fmaxf(mx, o[jj]);
    mx = fmaxf(mx, __shfl_xor(mx, 1));
    mx = fmaxf(mx, __shfl_xor(mx, 2));
    unsigned int p[8];
    #pragma unroll
    for (int jj = 0; jj < 8; ++jj)
      p[jj] = cvt_pk_bf16(__expf(o[2*jj] - mx), __expf(o[2*jj+1] - mx));
    // store in PV A-frag order: [sr][kk][q4*16+n16][8]
    const int kk = qr >> 1, q4b = (qr & 1) * 2, sr = r >> 4, n16r = r & 15;
    *(uint4*)(tb + (sr * 2 + kk) * 512 + (q4b * 16 + n16r) * 8)       = *(const uint4*)&p[0];
    *(uint4*)(tb + (sr * 2 + kk) * 512 + ((q4b + 1) * 16 + n16r) * 8) = *(const uint4*)&p[4];
    float s = 0.f;
    #pragma unroll
    for (int jj = 0; jj < 8; ++jj) s += bf_lo(p[jj]) + bf_hi(p[jj]);
    s += __shfl_xor(s, 1);
    s += __shfl_xor(s, 2);
    if (qr == 0) st[r] = make_float2(mx, s);
  }
}

// ---------------------------------------------------------------------------
// K3b: PV from fragment-ordered P and V2 (verified oo/kh-split), per-row
// (m, 1/l) stats computed inline (fixed-16 unroll, sentinel predication).
// Pp padded to stride 66 (~2-way banks).
// ---------------------------------------------------------------------------
__global__ __launch_bounds__(256) void pv_k(
    const bf16* __restrict__ conv_out, const bf16* __restrict__ V2,
    const float* __restrict__ tstats, const float* __restrict__ Vtail,
    const float* __restrict__ mix_w, const float* __restrict__ mix_b,
    const float* __restrict__ kq_b,
    const float* __restrict__ dyt_alpha, const float* __restrict__ dyt_w,
    const float* __restrict__ dyt_b, const float* __restrict__ depth_scale,
    bf16* __restrict__ out_attn)
{
  const int qt16 = blockIdx.x, g = blockIdx.y, b = blockIdx.z;
  const int qt = qt16 >> 2;
  const int nkt = min(qt + 2, 16);
  const int Tc = 1024 - (nkt << 6);
  const int tid = threadIdx.x, lane = tid & 63, wid = tid >> 6;
  const int q4 = lane >> 4, n16 = lane & 15;
  const int oo = wid >> 1, kh = wid & 1;
  const int h0 = 2 * g, ho = h0 + oo;
  const int sr = qt16 & 3, strow = sr * 16;
  const size_t tbase = (size_t)(qt * (qt + 3) / 2);

  // ---- inline combine: per-row (m, 1/l) for this block's 16 rows x 2 heads
  __shared__ float2 rsS[2][16];
  if (tid < 32) {
    const int hh = tid >> 4, rw = tid & 15;
    const float2* tsp = (const float2*)tstats +
        ((size_t)(b * 16 + h0 + hh) * 151 + tbase) * 64 + strow + rw;
    const float kb2 = kq_b[h0 + hh];
    float vx[16], vy[16];
    #pragma unroll
    for (int kt = 0; kt < 16; ++kt) {      // all 16 loads independent
      float2 v = tsp[(size_t)kt * 64];     // in-bounds: max idx 4831 < 4832
      vx[kt] = (kt < nkt) ? v.x : -3.0e38f;
      vy[kt] = (kt < nkt) ? v.y : 0.f;
    }
    float mx = (Tc > 0) ? kb2 : -3.0e38f;
    #pragma unroll
    for (int kt = 0; kt < 16; ++kt) mx = fmaxf(mx, vx[kt]);
    float s = (float)Tc * __expf(kb2 - mx);
    #pragma unroll
    for (int kt = 0; kt < 16; ++kt) s += vy[kt] * __expf(vx[kt] - mx);
    rsS[hh][rw] = make_float2(mx, 1.f / s);
  }
  __syncthreads();

  const float2 r0 = rsS[0][n16];
  const float2 r1 = rsS[1][n16];
  const float m0 = r0.x, m1 = r1.x;
  const float mwa = mix_w[ho * 2 + 0], mwb = mix_w[ho * 2 + 1];
  const float wa = mwa * r0.y, wb = mwb * r1.y;   // mw * rinv

  const bf16* pb0 = conv_out +
      ((size_t)(b * 16 + h0) * 151 + tbase) * 4096 + sr * 1024 + lane * 8;
  const bf16* pb1 = pb0 + (size_t)151 * 4096;
  const float2* ts0 = (const float2*)tstats +
      ((size_t)(b * 16 + h0) * 151 + tbase) * 64 + strow + n16;
  const float2* ts1 = ts0 + (size_t)151 * 64;
  const bf16* vb = V2 + ((size_t)(b * 16 + ho) << 16) + lane * 8;

  const int niter = (nkt - kh + 1) >> 1;
  float wk0[8], wk1[8];
  #pragma unroll
  for (int i = 0; i < 8; ++i) {
    int ktc = (i < niter) ? (kh + 2 * i) : 0;
    wk0[i] = wa * __expf(ts0[(size_t)ktc * 64].x - m0);
    wk1[i] = wb * __expf(ts1[(size_t)ktc * 64].x - m1);
  }

  f32x4 acc[4] = {};
  int ii = 0;
  for (int kt = kh; kt < nkt; kt += 2, ++ii) {
    uint4 u0[2], u1[2];
    #pragma unroll
    for (int kk = 0; kk < 2; ++kk) {
      u0[kk] = *(const uint4*)(pb0 + (size_t)kt * 4096 + kk * 512);
      u1[kk] = *(const uint4*)(pb1 + (size_t)kt * 4096 + kk * 512);
    }
    bf16x8 bv[2][4];
    #pragma unroll
    for (int kk = 0; kk < 2; ++kk)
      #pragma unroll
      for (int ctt = 0; ctt < 4; ++ctt)
        bv[kk][ctt] = *(const bf16x8*)(vb + (size_t)kt * 4096 + kk * 2048 + ctt * 512);
    const float w0 = wk0[ii], w1 = wk1[ii];
    #pragma unroll
    for (int kk = 0; kk < 2; ++kk) {
      bf16x8 af;
      const unsigned int* a0p = (const unsigned int*)&u0[kk];
      const unsigned int* a1p = (const unsigned int*)&u1[kk];
      #pragma unroll
      for (int i2 = 0; i2 < 4; ++i2) {
        float a0 = w0 * bf_lo(a0p[i2]) + w1 * bf_lo(a1p[i2]);
        float a1 = w0 * bf_hi(a0p[i2]) + w1 * bf_hi(a1p[i2]);
        ((unsigned int*)&af)[i2] = cvt_pk_bf16(a0, a1);
      }
      #pragma unroll
      for (int ctt = 0; ctt < 4; ++ctt)
        acc[ctt] = __builtin_amdgcn_mfma_f32_16x16x32_bf16(af, bv[kk][ctt], acc[ctt], 0, 0, 0);
    }
  }

  __shared__ float Pp[2][16][66];   // stride 66: ~2-way banks
  if (kh == 1) {
    #pragma unroll
    for (int ctt = 0; ctt < 4; ++ctt)
      #pragma unroll
      for (int r = 0; r < 4; ++r)
        Pp[oo][q4 * 4 + r][ctt * 16 + n16] = acc[ctt][r];
  }
  __syncthreads();
  if (kh == 1) return;
  #pragma unroll
  for (int ctt = 0; ctt < 4; ++ctt)
    #pragma unroll
    for (int r = 0; r < 4; ++r)
      acc[ctt][r] += Pp[oo][q4 * 4 + r][ctt * 16 + n16];

  const float kqb0 = kq_b[h0], kqb1 = kq_b[h0 + 1];
  float tw[4];
  #pragma unroll
  for (int r = 0; r < 4; ++r) {
    float2 s0 = rsS[0][q4 * 4 + r];
    float2 s1 = rsS[1][q4 * 4 + r];
    tw[r] = (Tc > 0) ? (mwa * s0.y * __expf(kqb0 - s0.x) +
                        mwb * s1.y * __expf(kqb1 - s1.x)) : 0.f;
  }
  const float mb = mix_b[ho];
  const float alpha = dyt_alpha[0], dsc = depth_scale[0];
  const float* vt = Vtail + (size_t)(b * 16 + ho) * 17 * 64;
  #pragma unroll
  for (int ctt = 0; ctt < 4; ++ctt) {
    int d = ctt * 16 + n16;
    float vtn = vt[(size_t)nkt * 64 + d];
    float vt0 = vt[d];
    float wgt = dyt_w[d], bds = dyt_b[d];
    #pragma unroll
    for (int r = 0; r < 4; ++r) {
      float v = acc[ctt][r] + tw[r] * vtn + mb * vt0;
      float e = __expf(2.f * alpha * v);
      float th = 1.f - 2.f / (e + 1.f);
      float y = (th * wgt + bds) * dsc;
      int qr = qt16 * 16 + q4 * 4 + r;
      out_attn[(((size_t)(b * 1024 + qr)) << 10) + ho * 64 + d] = (bf16)y;
    }
  }
}

// ---------------------------------------------------------------------------
extern "C" void kernel_launch(void* const* d_in, const int* in_sizes, int n_in,
                              void* d_out, int out_size, void* d_ws, size_t ws_size,
                              hipStream_t stream) {
  const float* Q    = (const float*)d_in[0];
  const float* Kx   = (const float*)d_in[1];
  const float* V    = (const float*)d_in[2];
  const float* Wq   = (const float*)d_in[3];
  const float* bq   = (const float*)d_in[4];
  const float* Wk   = (const float*)d_in[5];
  const float* bk   = (const float*)d_in[6];
  const float* Wv   = (const float*)d_in[7];
  const float* bv   = (const float*)d_in[8];
  const float* Wo   = (const float*)d_in[9];
  const float* bo   = (const float*)d_in[10];
  const float* kq_w = (const float*)d_in[11];
  const float* kq_b = (const float*)d_in[12];
  const float* mixw = (const float*)d_in[13];
  const float* mixb = (const float*)d_in[14];
  const float* dyta = (const float*)d_in[15];
  const float* dytw = (const float*)d_in[16];
  const float* dytb = (const float*)d_in[17];
  const float* dsc  = (const float*)d_in[18];

  char* ws = (char*)d_ws;
  bf16* qh     = (bf16*)(ws);                              // 4 MB (kh, V2 follow)
  float* tstat = (float*)(ws + (size_t)(12 << 20));        // 2.42 MB (alive thru pv)
  float* Vtail = (float*)(ws + (size_t)(16 << 20));        // 136 KB
  float* Tsum  = (float*)(ws + (size_t)(16 << 20) + (256 << 10)); // 128 KB
  bf16* WtT    = (bf16*)(ws + (size_t)(17 << 20));         // 8 MB (4 planes x 2MB)
  bf16* oat    = (bf16*)(ws + (size_t)(17 << 20));         // 4 MB, aliases Wq/Wk planes
  bf16* conv   = (bf16*)(ws + (size_t)(25 << 20));         // 39.58 MB (P2 tiles)
  bf16* Ab     = (bf16*)(ws + (size_t)(25 << 20));         // 12 MB, aliases conv (dead then)
  bf16* kh     = qh + ((size_t)1 << 21);
  bf16* V2     = qh + ((size_t)2 << 21);

  prep_k<<<dim3(4096), 256, 0, stream>>>(Wq, Wk, Wv, Wo, Q, Kx, V, WtT, Ab);
  proj_gemm_k<<<dim3(256, 1, 3), 256, 0, stream>>>(Ab, WtT, bq, bk, bv, qh, Tsum);
  logits_conv_k<<<dim3(152, 16, 2), 320, 0, stream>>>(qh, kh, kq_w, kq_b, conv, tstat,
                                                      Tsum, Vtail);
  pv_k<<<dim3(64, 8, 2), 256, 0, stream>>>(conv, V2, tstat, Vtail, mixw, mixb, kq_b,
                                           dyta, dytw, dytb, dsc, oat);
  out_gemm_k<<<dim3(512), 256, 0, stream>>>(oat, WtT + ((size_t)3 << 20), bo, (float*)d_out);
}